// Round 9
// baseline (931.166 us; speedup 1.0000x reference)
//
#include <hip/hip_runtime.h>
#include <hip/hip_bf16.h>
#include <hip/hip_fp16.h>

// Problem: B=8192, T=128, D=7, I=128, C=10, H=64, L=128
// R23: SINGLE plain kernel (1024 blocks) = R19 prep+main merged.
//   Phase 0 (duty): blk 0..63 attn (4x 1-wave units), 64..95 leaf softmax
//     (4x per-wave trees), 96..135 zero out. x/mask f32->bf16 cvt moved INTO
//     main phase 1 (cvt8 per lane) -> xbf/mbf buffers & their prep blocks gone.
//   Gate: 136 ws slots, producer fence+syncthreads+atomic-release MAGIC;
//     all blocks spin (acquire, bounded ~40ms -> fail visibly, never hang).
//     Re-poison rewrites slots every iteration; MAGIC has no repeated bytes.
//   Phase B: R19-verified main (zsl LDS, lpt double-buffer, atomic epilogue).
//   Co-residency: 1024 blocks = 256 CU x 4; launch_bounds(256,4), LDS 24.6KB
//     (4x24.6=98KB<160), waves 16/CU, VGPR cap 128 -> all resident at t=0.
// ws layout (float slots):
//   attnB fp16 [8192][128] off 0        (524288)
//   LPb   uint4 compact    off 524288   (81920)   [t][s][n<10][hf]
//   slots uint  [136]      off 606208

#define BB 8192
#define TT 128
#define II 128
#define CC 10
#define HH 64

#define OFF_LPB  524288
#define OFF_SLOT 606208
#define NSLOT 136
#define MAGIC 0x5A17C0DEu

typedef __attribute__((ext_vector_type(8))) short short8;
typedef __attribute__((ext_vector_type(16))) float floatx16;

static __device__ inline unsigned int pkbf(float lo, float hi) {
  __hip_bfloat162 h = __float22bfloat162_rn(make_float2(lo, hi));
  unsigned int u;
  __builtin_memcpy(&u, &h, 4);
  return u;
}

static __device__ inline unsigned int pkh(float lo, float hi) {
  __half2 h = __float22half2_rn(make_float2(lo, hi));
  unsigned int u;
  __builtin_memcpy(&u, &h, 4);
  return u;
}

static __device__ inline short8 cvt8(float4 a, float4 b) {
  union { short8 v; unsigned int u[4]; } r;
  r.u[0] = pkbf(a.x, a.y);
  r.u[1] = pkbf(a.z, a.w);
  r.u[2] = pkbf(b.x, b.y);
  r.u[3] = pkbf(b.z, b.w);
  return r.v;
}

__global__ __launch_bounds__(256, 4) void fused_kernel(
    const float* __restrict__ x, const float* __restrict__ mask,
    const float* __restrict__ thr, const float* __restrict__ lo,
    const float* __restrict__ W1, const float* __restrict__ b1,
    const float* __restrict__ W2, const float* __restrict__ b2,
    __half* __restrict__ attnB, unsigned int* __restrict__ lpbG,
    unsigned int* __restrict__ slots, float* __restrict__ out) {
  __shared__ __align__(16) char smem_raw[24576];
  const int blk = blockIdx.x;
  const int tid = threadIdx.x;
  const int wv = tid >> 6, lane = tid & 63;
  const int half = lane >> 5, l31 = lane & 31;

  // ==================== Phase 0: duties (blocks 0..135) =====================
  if (blk < 64) {
    // -------- attn: 4 one-wave units of 32 rows (R19-verified math) ---------
    const int b0 = blk * 128 + wv * 32;

    short8 axf[8];
    const float* xrow = x + (size_t)(b0 + l31) * II + half * 8;
#pragma unroll
    for (int s = 0; s < 8; ++s)
      axf[s] = cvt8(*(const float4*)(xrow + s * 16),
                    *(const float4*)(xrow + s * 16 + 4));

    floatx16 acch[2];
#pragma unroll
    for (int i = 0; i < 16; ++i) { acch[0][i] = 0.f; acch[1][i] = 0.f; }
#pragma unroll
    for (int s = 0; s < 8; ++s) {
#pragma unroll
      for (int tile = 0; tile < 2; ++tile) {
        union { short8 v; unsigned int u[4]; } wf;
#pragma unroll
        for (int jp = 0; jp < 4; ++jp) {
          int k0 = s * 16 + half * 8 + jp * 2;
          float f0 = W1[(size_t)k0 * HH + tile * 32 + l31];
          float f1 = W1[(size_t)(k0 + 1) * HH + tile * 32 + l31];
          wf.u[jp] = pkbf(f0, f1);
        }
        acch[tile] = __builtin_amdgcn_mfma_f32_32x32x16_bf16(
            axf[s], wf.v, acch[tile], 0, 0, 0);
      }
    }
    __hip_bfloat16* hids = (__hip_bfloat16*)(smem_raw + wv * 4608);  // [32][72]
#pragma unroll
    for (int tile = 0; tile < 2; ++tile) {
      float bh = b1[tile * 32 + l31];
#pragma unroll
      for (int r = 0; r < 16; ++r) {
        int row = (r & 3) + 8 * (r >> 2) + 4 * half;
        hids[row * 72 + tile * 32 + l31] =
            __float2bfloat16(fmaxf(acch[tile][r] + bh, 0.f));
      }
    }
    __syncthreads();

    short8 ahf[4];
#pragma unroll
    for (int s = 0; s < 4; ++s)
      ahf[s] = *(const short8*)(hids + l31 * 72 + s * 16 + half * 8);

    floatx16 accl[4];
#pragma unroll
    for (int tile = 0; tile < 4; ++tile) {
#pragma unroll
      for (int i = 0; i < 16; ++i) accl[tile][i] = 0.f;
#pragma unroll
      for (int s = 0; s < 4; ++s) {
        union { short8 v; unsigned int u[4]; } wf;
#pragma unroll
        for (int jp = 0; jp < 4; ++jp) {
          int k0 = s * 16 + half * 8 + jp * 2;
          float f0 = W2[(size_t)k0 * TT + tile * 32 + l31];
          float f1 = W2[(size_t)(k0 + 1) * TT + tile * 32 + l31];
          wf.u[jp] = pkbf(f0, f1);
        }
        accl[tile] = __builtin_amdgcn_mfma_f32_32x32x16_bf16(
            ahf[s], wf.v, accl[tile], 0, 0, 0);
      }
      float bt = b2[tile * 32 + l31];
#pragma unroll
      for (int i = 0; i < 16; ++i) accl[tile][i] += bt;
    }

    float mrow[16];
#pragma unroll
    for (int r = 0; r < 16; ++r)
      mrow[r] = fmaxf(fmaxf(accl[0][r], accl[1][r]),
                      fmaxf(accl[2][r], accl[3][r]));
#pragma unroll
    for (int msk = 1; msk <= 16; msk <<= 1)
#pragma unroll
      for (int r = 0; r < 16; ++r)
        mrow[r] = fmaxf(mrow[r], __shfl_xor(mrow[r], msk, 64));
    float srow[16];
#pragma unroll
    for (int r = 0; r < 16; ++r) srow[r] = 0.f;
#pragma unroll
    for (int tile = 0; tile < 4; ++tile)
#pragma unroll
      for (int r = 0; r < 16; ++r) {
        float e = __expf(accl[tile][r] - mrow[r]);
        accl[tile][r] = e;
        srow[r] += e;
      }
#pragma unroll
    for (int msk = 1; msk <= 16; msk <<= 1)
#pragma unroll
      for (int r = 0; r < 16; ++r)
        srow[r] += __shfl_xor(srow[r], msk, 64);
#pragma unroll
    for (int r = 0; r < 16; ++r) srow[r] = 1.f / srow[r];

#pragma unroll
    for (int tile = 0; tile < 4; ++tile)
#pragma unroll
      for (int r = 0; r < 16; ++r) {
        int row = (r & 3) + 8 * (r >> 2) + 4 * half;
        attnB[(size_t)(b0 + row) * TT + tile * 32 + l31] =
            __float2half(accl[tile][r] * srow[r]);
      }

  } else if (blk < 96) {
    // -------- leaf softmax: 4 per-wave trees -> COMPACT fp16 B-frags --------
    float* lps = (float*)(smem_raw + wv * 6144);   // [128][12] f32
    const int t0 = (blk - 64) * 4 + wv;
#pragma unroll
    for (int rr = 0; rr < 2; ++rr) {
      int l = lane * 2 + rr;         // 0..127
      const float* row = lo + ((size_t)t0 * 128 + l) * CC;
      float v[CC];
      float m = -1e30f;
#pragma unroll
      for (int c = 0; c < CC; ++c) { v[c] = row[c]; m = fmaxf(m, v[c]); }
      float s = 0.f;
#pragma unroll
      for (int c = 0; c < CC; ++c) { v[c] = __expf(v[c] - m); s += v[c]; }
      float inv = 1.f / s;
      float* o = lps + l * 12;
#pragma unroll
      for (int c = 0; c < CC; ++c) o[c] = v[c] * inv;
    }
    __syncthreads();   // orders cross-lane LDS (waves symmetric)

    // layout: idx = tree*160 + s*20 + n*2 + hf  (uint4)
#pragma unroll
    for (int jj = 0; jj < 3; ++jj) {
      int idx = jj * 64 + lane;      // 0..191
      if (idx < 160) {
        int s = idx / 20, e = idx - s * 20;
        int n = e >> 1, hf = e & 1;
        unsigned int wd[4];
#pragma unroll
        for (int jp = 0; jp < 4; ++jp) {
          int l0 = s * 16 + hf * 8 + jp * 2;
          float f0 = lps[l0 * 12 + n];
          float f1 = lps[(l0 + 1) * 12 + n];
          wd[jp] = pkh(f0, f1);
        }
        ((uint4*)lpbG)[(size_t)t0 * 160 + idx] =
            make_uint4(wd[0], wd[1], wd[2], wd[3]);
      }
    }
  } else if (blk < 136) {
    // -------- zero out (re-zeroed EVERY launch; atomics follow) -------------
    const int b4 = (blk - 96) * 512;
    ((float4*)out)[b4 + tid] = make_float4(0.f, 0.f, 0.f, 0.f);
    ((float4*)out)[b4 + 256 + tid] = make_float4(0.f, 0.f, 0.f, 0.f);
  }

  // -------- signal (producers) then gate (everyone) -------------------------
  if (blk < NSLOT) {
    __threadfence();                 // each thread's stores agent-visible
    __syncthreads();                 // all threads' fences done
    if (tid == 0)
      __hip_atomic_store(&slots[blk], MAGIC, __ATOMIC_RELEASE,
                         __HIP_MEMORY_SCOPE_AGENT);
  }
  if (tid < NSLOT) {
    int guard = 0;
    while (__hip_atomic_load(&slots[tid], __ATOMIC_ACQUIRE,
                             __HIP_MEMORY_SCOPE_AGENT) != MAGIC) {
      __builtin_amdgcn_s_sleep(4);
      if (++guard > 300000) break;   // ~40ms valve: fail visibly, never hang
    }
  }
  __syncthreads();
  __threadfence();                   // acquire: drop stale L1/L2 lines

  // ==================== Phase B: main (all 1024 blocks) =====================
  // (R19-verified structure; x/mask f32 loaded + cvt8 in-kernel)
  {
    const int phys = blk;
    const int bg2 = (phys & 7) + ((phys >> 7) << 3);  // same-bg2 -> same XCD
    const int tg  = (phys >> 3) & 15;
    const int bl = wv * 32 + l31;      // own local row 0..127

    __half* zsl = (__half*)smem_raw;   // [8 tree][128 row][8]

    // early load: attn vector for own row (hides under phase 1)
    __half av[8];
    *(uint4*)av = ((const uint4*)attnB)[(size_t)(bg2 * 128 + bl) * 16 + tg];

    // ---------------- zs -> LDS (per-wave rows) -----------------------------
    {
      const int m0 = tg * 56;
      short8 xf[8];
      const float* xr = x + (size_t)(bg2 * 128 + bl) * II + half * 8;
#pragma unroll
      for (int s = 0; s < 8; ++s)
        xf[s] = cvt8(*(const float4*)(xr + s * 16),
                     *(const float4*)(xr + s * 16 + 4));

#pragma unroll
      for (int tile = 0; tile < 2; ++tile) {
        int mr = m0 + tile * 28 + l31; if (mr > 895) mr = 895;
        const float* mrow = mask + (size_t)mr * II + half * 8;

        floatx16 acc;
#pragma unroll
        for (int i = 0; i < 16; ++i) acc[i] = 0.f;
#pragma unroll
        for (int s = 0; s < 8; ++s) {
          short8 af = cvt8(*(const float4*)(mrow + s * 16),
                           *(const float4*)(mrow + s * 16 + 4));
          acc = __builtin_amdgcn_mfma_f32_32x32x16_bf16(af, xf[s], acc, 0, 0, 0);
        }

#pragma unroll
        for (int r = 0; r < 16; ++r) {
          int row = (r & 3) + 8 * (r >> 2) + 4 * half;   // m-local 0..31
          if (row < 28) {
            int tl = row / 7;
            int d = row - tl * 7;
            float z = acc[r] - thr[m0 + tile * 28 + row];
            float o = 0.5f * (z / (1.f + fabsf(z)) + 1.f);
            zsl[((tl + tile * 4) * 128 + bl) * 8 + d] = __float2half(o);
          }
        }
      }
    }
    // NO barrier: each wave reads only the zsl rows it wrote

    // ---------------- contraction, double-buffered lpt ----------------------
    const uint4* zsl4 = (const uint4*)smem_raw;
    const uint4* lpt = (const uint4*)lpbG + (size_t)tg * 1280;

    floatx16 acc;
#pragma unroll
    for (int i = 0; i < 16; ++i) acc[i] = 0.f;

    auto dostep = [&](int it, const uint4* bf) {
      uint4 sv = zsl4[it * 128 + bl];
      const __half* sh = (const __half*)&sv;
      float s0 = __half2float(sh[0]), s1 = __half2float(sh[1]);
      float s2 = __half2float(sh[2]), s3 = __half2float(sh[3]);
      float s4 = __half2float(sh[4]), s5 = __half2float(sh[5]);
      float s6 = __half2float(sh[6]);
      float A  = __half2float(av[it]);

      float s0c = 1.f - s0, s1c = 1.f - s1, s2c = 1.f - s2;
      float t0 = s0 * s1, t1 = s0c * s1, t2 = s0 * s1c, t3 = s0c * s1c;
      float pl[8];
      pl[0] = t0 * s2;  pl[1] = t1 * s2;  pl[2] = t2 * s2;  pl[3] = t3 * s2;
      pl[4] = t0 * s2c; pl[5] = t1 * s2c; pl[6] = t2 * s2c; pl[7] = t3 * s2c;
      float sel3 = half ? (1.f - s3) : s3;
      float Af = A * sel3;
      float s4c = 1.f - s4, s5c = 1.f - s5;
      float as6 = Af * s6, as6c = Af * (1.f - s6);
      float u0 = s4 * s5, u1 = s4c * s5, u2 = s4 * s5c, u3 = s4c * s5c;
      float wv8[8];
      wv8[0] = u0 * as6;  wv8[1] = u1 * as6;
      wv8[2] = u2 * as6;  wv8[3] = u3 * as6;
      wv8[4] = u0 * as6c; wv8[5] = u1 * as6c;
      wv8[6] = u2 * as6c; wv8[7] = u3 * as6c;
      __half2 pl2[4];
#pragma unroll
      for (int jp = 0; jp < 4; ++jp)
        pl2[jp] = __float22half2_rn(make_float2(pl[jp * 2], pl[jp * 2 + 1]));

#pragma unroll
      for (int s = 0; s < 8; ++s) {
        union { short8 v; __half2 h[4]; } a0;
        __half2 w2 = __half2half2(__float2half(wv8[s]));
#pragma unroll
        for (int jp = 0; jp < 4; ++jp) a0.h[jp] = __hmul2(pl2[jp], w2);
        acc = __builtin_amdgcn_mfma_f32_32x32x16_f16(
            a0.v, *(const short8*)&bf[s], acc, 0, 0, 0);
      }
    };

#define PF(dst, itn)                                                       \
  _Pragma("unroll") for (int s = 0; s < 8; ++s)                            \
      dst[s] = (l31 < CC) ? lpt[((itn) * 8 + s) * 20 + l31 * 2 + half]     \
                          : make_uint4(0u, 0u, 0u, 0u);

    uint4 bf0[8], bf1[8];
    PF(bf0, 0)
#pragma unroll
    for (int ith = 0; ith < 4; ++ith) {
      const int it = ith * 2;
      PF(bf1, it + 1)            // issue next-tree loads...
      dostep(it, bf0);           // ...hidden under this tree's VALU+MFMA
      if (ith < 3) { PF(bf0, it + 2) }
      dostep(it + 1, bf1);
    }
#undef PF

    // -------- epilogue: red overlays zsl (barrier both sides) ---------------
    __syncthreads();   // every wave done reading its zsl before overlay write
    float* red = (float*)smem_raw;   // [128][10] f32 = 5120 B
    if (l31 < CC) {
#pragma unroll
      for (int r = 0; r < 16; ++r) {
        int row = (r & 3) + 8 * (r >> 2) + 4 * half;
        red[(wv * 32 + row) * 10 + l31] = acc[r];
      }
    }
    __syncthreads();
#pragma unroll
    for (int j = 0; j < 5; ++j) {
      int idx = tid + 256 * j;   // 0..1279
      atomicAdd(out + (size_t)bg2 * 1280 + idx, red[idx]);
    }
  }
}

// ---------------------------------------------------------------------------
extern "C" void kernel_launch(void* const* d_in, const int* in_sizes, int n_in,
                              void* d_out, int out_size, void* d_ws, size_t ws_size,
                              hipStream_t stream) {
  const float* x    = (const float*)d_in[0];
  const float* mask = (const float*)d_in[1];
  const float* thr  = (const float*)d_in[2];
  const float* lo   = (const float*)d_in[3];
  const float* W1   = (const float*)d_in[4];
  const float* b1   = (const float*)d_in[5];
  const float* W2   = (const float*)d_in[6];
  const float* b2   = (const float*)d_in[7];
  float* out = (float*)d_out;
  float* ws  = (float*)d_ws;

  __half*       attnB = (__half*)ws;
  unsigned int* LPb   = (unsigned int*)(ws + OFF_LPB);
  unsigned int* slots = (unsigned int*)(ws + OFF_SLOT);

  fused_kernel<<<1024, 256, 0, stream>>>(x, mask, thr, lo, W1, b1, W2, b2,
                                         attnB, LPb, slots, out);
}

// Round 10
// 166.208 us; speedup vs baseline: 5.6024x; 5.6024x over previous
//
#include <hip/hip_runtime.h>
#include <hip/hip_bf16.h>
#include <hip/hip_fp16.h>

// Problem: B=8192, T=128, D=7, I=128, C=10, H=64, L=128
// R24 = R19 (verified best, 101.7us) with main re-gridded for 32 waves/CU:
//   grid 2048 = (bg2 0..63 x tg8 0..31); each wave: 32 rows x 4 trees
//   (it-loop 4, m-tile 28 rows). launch_bounds(256,8): 8 blocks/CU x 4 waves
//   = 32 waves/CU (2x R19) -- fits because this code compiles to 64 VGPR
//   (R3/R8 profiles) and LDS is 8KB/block (zsl[4][128][8]).
//   Everything else is R19 per-wave structure verbatim: zsl LDS (no phase
//   barrier), lpt reg double-buffer from L2, atomic epilogue via red overlay.
//   (R21 regression attributed to its lpt-LDS-stage + barrier + 24w/CU, not
//   to the tree split; R23's fused-kernel spill lesson: attn stays in prep.)
// ws layout (float slots):
//   attnB fp16 [8192][128] off 0        (524288)
//   LPb   uint4 compact    off 524288   (81920)   [t][s][n<10][hf]
//   xbf   bf16 [8192][128] off 606208   (524288)
//   mbf   bf16 [896][128]  off 1130496  (57344)

#define BB 8192
#define TT 128
#define II 128
#define CC 10
#define HH 64

#define OFF_LPB 524288
#define OFF_XBF 606208
#define OFF_MBF 1130496

typedef __attribute__((ext_vector_type(8))) short short8;
typedef __attribute__((ext_vector_type(16))) float floatx16;

static __device__ inline unsigned int pkbf(float lo, float hi) {
  __hip_bfloat162 h = __float22bfloat162_rn(make_float2(lo, hi));
  unsigned int u;
  __builtin_memcpy(&u, &h, 4);
  return u;
}

static __device__ inline unsigned int pkh(float lo, float hi) {
  __half2 h = __float22half2_rn(make_float2(lo, hi));
  unsigned int u;
  __builtin_memcpy(&u, &h, 4);
  return u;
}

static __device__ inline short8 cvt8(float4 a, float4 b) {
  union { short8 v; unsigned int u[4]; } r;
  r.u[0] = pkbf(a.x, a.y);
  r.u[1] = pkbf(a.z, a.w);
  r.u[2] = pkbf(b.x, b.y);
  r.u[3] = pkbf(b.z, b.w);
  return r.v;
}

// ---- prep: 708 blocks x 64 thr (R19-verified, unchanged) -------------------
// [0,256): attn, 32 rows/block (one wave)
// [256,384): leaf softmax, 1 tree/block
// [384,640): x f32->bf16, 4096 elems/block
// [640,668): mask f32->bf16, 4096 elems/block
// [668,708): zero out, 512 float4/block
__global__ __launch_bounds__(64) void prep_kernel(
    const float* __restrict__ x, const float* __restrict__ mask,
    const float* __restrict__ lo,
    const float* __restrict__ W1, const float* __restrict__ b1,
    const float* __restrict__ W2, const float* __restrict__ b2,
    __half* __restrict__ attnB, unsigned int* __restrict__ lpbG,
    unsigned short* __restrict__ xbf, unsigned short* __restrict__ mbf,
    float* __restrict__ out) {
  __shared__ __align__(16) char smem_raw[6144];
  const int blk = blockIdx.x;
  const int lane = threadIdx.x;           // 0..63 (one wave)
  const int half = lane >> 5, l31 = lane & 31;

  if (blk < 256) {
    // ---------------- attn: 32 rows, one wave -------------------------------
    const int b0 = blk * 32;

    short8 axf[8];
    const float* xrow = x + (size_t)(b0 + l31) * II + half * 8;
#pragma unroll
    for (int s = 0; s < 8; ++s)
      axf[s] = cvt8(*(const float4*)(xrow + s * 16),
                    *(const float4*)(xrow + s * 16 + 4));

    floatx16 acch[2];
#pragma unroll
    for (int i = 0; i < 16; ++i) { acch[0][i] = 0.f; acch[1][i] = 0.f; }
#pragma unroll
    for (int s = 0; s < 8; ++s) {
#pragma unroll
      for (int tile = 0; tile < 2; ++tile) {
        union { short8 v; unsigned int u[4]; } wf;
#pragma unroll
        for (int jp = 0; jp < 4; ++jp) {
          int k0 = s * 16 + half * 8 + jp * 2;
          float f0 = W1[(size_t)k0 * HH + tile * 32 + l31];
          float f1 = W1[(size_t)(k0 + 1) * HH + tile * 32 + l31];
          wf.u[jp] = pkbf(f0, f1);
        }
        acch[tile] = __builtin_amdgcn_mfma_f32_32x32x16_bf16(
            axf[s], wf.v, acch[tile], 0, 0, 0);
      }
    }
    __hip_bfloat16* hids = (__hip_bfloat16*)smem_raw;   // [32][72]
#pragma unroll
    for (int tile = 0; tile < 2; ++tile) {
      float bh = b1[tile * 32 + l31];
#pragma unroll
      for (int r = 0; r < 16; ++r) {
        int row = (r & 3) + 8 * (r >> 2) + 4 * half;
        hids[row * 72 + tile * 32 + l31] =
            __float2bfloat16(fmaxf(acch[tile][r] + bh, 0.f));
      }
    }
    __syncthreads();

    short8 ahf[4];
#pragma unroll
    for (int s = 0; s < 4; ++s)
      ahf[s] = *(const short8*)(hids + l31 * 72 + s * 16 + half * 8);

    floatx16 accl[4];
#pragma unroll
    for (int tile = 0; tile < 4; ++tile) {
#pragma unroll
      for (int i = 0; i < 16; ++i) accl[tile][i] = 0.f;
#pragma unroll
      for (int s = 0; s < 4; ++s) {
        union { short8 v; unsigned int u[4]; } wf;
#pragma unroll
        for (int jp = 0; jp < 4; ++jp) {
          int k0 = s * 16 + half * 8 + jp * 2;
          float f0 = W2[(size_t)k0 * TT + tile * 32 + l31];
          float f1 = W2[(size_t)(k0 + 1) * TT + tile * 32 + l31];
          wf.u[jp] = pkbf(f0, f1);
        }
        accl[tile] = __builtin_amdgcn_mfma_f32_32x32x16_bf16(
            ahf[s], wf.v, accl[tile], 0, 0, 0);
      }
      float bt = b2[tile * 32 + l31];
#pragma unroll
      for (int i = 0; i < 16; ++i) accl[tile][i] += bt;
    }

    float mrow[16];
#pragma unroll
    for (int r = 0; r < 16; ++r)
      mrow[r] = fmaxf(fmaxf(accl[0][r], accl[1][r]),
                      fmaxf(accl[2][r], accl[3][r]));
#pragma unroll
    for (int msk = 1; msk <= 16; msk <<= 1)
#pragma unroll
      for (int r = 0; r < 16; ++r)
        mrow[r] = fmaxf(mrow[r], __shfl_xor(mrow[r], msk, 64));
    float srow[16];
#pragma unroll
    for (int r = 0; r < 16; ++r) srow[r] = 0.f;
#pragma unroll
    for (int tile = 0; tile < 4; ++tile)
#pragma unroll
      for (int r = 0; r < 16; ++r) {
        float e = __expf(accl[tile][r] - mrow[r]);
        accl[tile][r] = e;
        srow[r] += e;
      }
#pragma unroll
    for (int msk = 1; msk <= 16; msk <<= 1)
#pragma unroll
      for (int r = 0; r < 16; ++r)
        srow[r] += __shfl_xor(srow[r], msk, 64);
#pragma unroll
    for (int r = 0; r < 16; ++r) srow[r] = 1.f / srow[r];

#pragma unroll
    for (int tile = 0; tile < 4; ++tile)
#pragma unroll
      for (int r = 0; r < 16; ++r) {
        int row = (r & 3) + 8 * (r >> 2) + 4 * half;
        attnB[(size_t)(b0 + row) * TT + tile * 32 + l31] =
            __float2half(accl[tile][r] * srow[r]);
      }

  } else if (blk < 384) {
    // ------- leaf softmax (1 tree) -> COMPACT fp16 B-frags ------------------
    float* lps = (float*)smem_raw;   // [128][12] f32 = 6144 B
    const int t0 = blk - 256;
#pragma unroll
    for (int rr = 0; rr < 2; ++rr) {
      int l = lane * 2 + rr;         // 0..127
      const float* row = lo + ((size_t)t0 * 128 + l) * CC;
      float v[CC];
      float m = -1e30f;
#pragma unroll
      for (int c = 0; c < CC; ++c) { v[c] = row[c]; m = fmaxf(m, v[c]); }
      float s = 0.f;
#pragma unroll
      for (int c = 0; c < CC; ++c) { v[c] = __expf(v[c] - m); s += v[c]; }
      float inv = 1.f / s;
      float* o = lps + l * 12;
#pragma unroll
      for (int c = 0; c < CC; ++c) o[c] = v[c] * inv;
    }
    __syncthreads();

    // layout: idx = tree*160 + s*20 + n*2 + hf  (uint4)
#pragma unroll
    for (int jj = 0; jj < 3; ++jj) {
      int idx = jj * 64 + lane;      // 0..191
      if (idx < 160) {
        int s = idx / 20, e = idx - s * 20;
        int n = e >> 1, hf = e & 1;
        unsigned int wd[4];
#pragma unroll
        for (int jp = 0; jp < 4; ++jp) {
          int l0 = s * 16 + hf * 8 + jp * 2;
          float f0 = lps[l0 * 12 + n];
          float f1 = lps[(l0 + 1) * 12 + n];
          wd[jp] = pkh(f0, f1);
        }
        ((uint4*)lpbG)[(size_t)t0 * 160 + idx] =
            make_uint4(wd[0], wd[1], wd[2], wd[3]);
      }
    }
  } else if (blk < 668) {
    // ------------- f32 -> bf16: x (256 blocks) / mask (28 blocks) -----------
    const float* src;
    unsigned short* dst;
    size_t base;
    if (blk < 640) { src = x;    dst = xbf; base = (size_t)(blk - 384) * 4096; }
    else           { src = mask; dst = mbf; base = (size_t)(blk - 640) * 4096; }
#pragma unroll
    for (int j = 0; j < 8; ++j) {
      size_t e = base + (size_t)j * 512 + (size_t)lane * 8;
      float4 a = *(const float4*)(src + e);
      float4 b = *(const float4*)(src + e + 4);
      *(short8*)(dst + e) = cvt8(a, b);
    }
  } else {
    // ------------- zero out (re-zeroed EVERY launch; atomics follow) --------
    const int base4 = (blk - 668) * 512;
#pragma unroll
    for (int j = 0; j < 8; ++j)
      ((float4*)out)[base4 + j * 64 + lane] = make_float4(0.f, 0.f, 0.f, 0.f);
  }
}

// -------- main: 2048 blocks = (bg2 0..63) x (tg8 0..31), 4 trees each -------
// Per wave: 32 rows x 4 trees (one 28-row m-tile). LDS 8KB (zsl[4][128][8],
// red overlays). launch_bounds(256,8): 8 blocks/CU = 32 waves/CU at <=64 VGPR.
__global__ __launch_bounds__(256, 8) void main_kernel(
    const unsigned short* __restrict__ xbf, const unsigned short* __restrict__ mbf,
    const float* __restrict__ thr, const __half* __restrict__ attnB,
    const unsigned int* __restrict__ lpbG, float* __restrict__ out) {
  __shared__ __align__(16) char smem_raw[8192];
  const int tid = threadIdx.x;
  const int wv = tid >> 6, lane = tid & 63;
  const int half = lane >> 5, l31 = lane & 31;
  const int phys = blockIdx.x;
  const int xcd = phys & 7;
  const int bg2 = xcd * 8 + ((phys >> 3) & 7);    // 0..63, chunked per XCD
  const int tg8 = phys >> 6;                      // 0..31: trees tg8*4..+4
  const int bl = wv * 32 + l31;                   // own local row 0..127

  __half* zsl = (__half*)smem_raw;                // [4 tree][128 row][8]

  // early load: attn vector for own row (hides under phase 1)
  // attnB row = 128 halves = 32 uint2 (uint2 = 4 halves); group tg8 -> +tg8.
  __half av[4];
  *(uint2*)av = ((const uint2*)attnB)[(size_t)(bg2 * 128 + bl) * 32 + tg8];

  // ==================== Phase 1: zs -> LDS (per-wave rows) ==================
  {
    const int m0 = tg8 * 28;
    short8 xf[8];
    const unsigned short* xr = xbf + (size_t)(bg2 * 128 + bl) * II + half * 8;
#pragma unroll
    for (int s = 0; s < 8; ++s) xf[s] = *(const short8*)(xr + s * 16);

    int mr = m0 + l31; if (mr > 895) mr = 895;   // A-pad clamp (tg8=31 only)
    const unsigned short* mrow = mbf + (size_t)mr * II + half * 8;

    floatx16 acc;
#pragma unroll
    for (int i = 0; i < 16; ++i) acc[i] = 0.f;
#pragma unroll
    for (int s = 0; s < 8; ++s) {
      short8 af = *(const short8*)(mrow + s * 16);
      acc = __builtin_amdgcn_mfma_f32_32x32x16_bf16(af, xf[s], acc, 0, 0, 0);
    }

#pragma unroll
    for (int r = 0; r < 16; ++r) {
      int row = (r & 3) + 8 * (r >> 2) + 4 * half;   // m-local 0..31
      if (row < 28) {                                // m0+row <= 895 always
        int tl = row / 7;
        int d = row - tl * 7;
        float z = acc[r] - thr[m0 + row];
        float o = 0.5f * (z / (1.f + fabsf(z)) + 1.f);
        zsl[((tl * 128) + bl) * 8 + d] = __float2half(o);
      }
    }
  }
  // NO barrier: each wave reads only the zsl rows it wrote

  // ==================== Phase 2: contraction (4 trees) ======================
  {
    const uint4* zsl4 = (const uint4*)smem_raw;
    const uint4* lpt = (const uint4*)lpbG + (size_t)tg8 * 640;

    floatx16 acc;
#pragma unroll
    for (int i = 0; i < 16; ++i) acc[i] = 0.f;

    auto dostep = [&](int it, const uint4* bf) {
      uint4 sv = zsl4[it * 128 + bl];
      const __half* sh = (const __half*)&sv;
      float s0 = __half2float(sh[0]), s1 = __half2float(sh[1]);
      float s2 = __half2float(sh[2]), s3 = __half2float(sh[3]);
      float s4 = __half2float(sh[4]), s5 = __half2float(sh[5]);
      float s6 = __half2float(sh[6]);
      float A  = __half2float(av[it]);

      float s0c = 1.f - s0, s1c = 1.f - s1, s2c = 1.f - s2;
      float t0 = s0 * s1, t1 = s0c * s1, t2 = s0 * s1c, t3 = s0c * s1c;
      float pl[8];
      pl[0] = t0 * s2;  pl[1] = t1 * s2;  pl[2] = t2 * s2;  pl[3] = t3 * s2;
      pl[4] = t0 * s2c; pl[5] = t1 * s2c; pl[6] = t2 * s2c; pl[7] = t3 * s2c;
      float sel3 = half ? (1.f - s3) : s3;
      float Af = A * sel3;
      float s4c = 1.f - s4, s5c = 1.f - s5;
      float as6 = Af * s6, as6c = Af * (1.f - s6);
      float u0 = s4 * s5, u1 = s4c * s5, u2 = s4 * s5c, u3 = s4c * s5c;
      float wv8[8];
      wv8[0] = u0 * as6;  wv8[1] = u1 * as6;
      wv8[2] = u2 * as6;  wv8[3] = u3 * as6;
      wv8[4] = u0 * as6c; wv8[5] = u1 * as6c;
      wv8[6] = u2 * as6c; wv8[7] = u3 * as6c;
      __half2 pl2[4];
#pragma unroll
      for (int jp = 0; jp < 4; ++jp)
        pl2[jp] = __float22half2_rn(make_float2(pl[jp * 2], pl[jp * 2 + 1]));

#pragma unroll
      for (int s = 0; s < 8; ++s) {
        union { short8 v; __half2 h[4]; } a0;
        __half2 w2 = __half2half2(__float2half(wv8[s]));
#pragma unroll
        for (int jp = 0; jp < 4; ++jp) a0.h[jp] = __hmul2(pl2[jp], w2);
        acc = __builtin_amdgcn_mfma_f32_32x32x16_f16(
            a0.v, *(const short8*)&bf[s], acc, 0, 0, 0);
      }
    };

#define PF(dst, itn)                                                       \
  _Pragma("unroll") for (int s = 0; s < 8; ++s)                            \
      dst[s] = (l31 < CC) ? lpt[((itn) * 8 + s) * 20 + l31 * 2 + half]     \
                          : make_uint4(0u, 0u, 0u, 0u);

    uint4 bf0[8], bf1[8];
    PF(bf0, 0)
#pragma unroll
    for (int ith = 0; ith < 2; ++ith) {
      const int it = ith * 2;
      PF(bf1, it + 1)            // issue next-tree loads...
      dostep(it, bf0);           // ...hidden under this tree's VALU+MFMA
      if (ith < 1) { PF(bf0, it + 2) }
      dostep(it + 1, bf1);
    }
#undef PF

    // -------- epilogue: red overlays zsl (barrier both sides) ---------------
    __syncthreads();   // every wave done reading its zsl before overlay write
    float* red = (float*)smem_raw;   // [128][10] f32 = 5120 B
    if (l31 < CC) {
#pragma unroll
      for (int r = 0; r < 16; ++r) {
        int row = (r & 3) + 8 * (r >> 2) + 4 * half;
        red[(wv * 32 + row) * 10 + l31] = acc[r];
      }
    }
    __syncthreads();
#pragma unroll
    for (int j = 0; j < 5; ++j) {
      int idx = tid + 256 * j;   // 0..1279
      atomicAdd(out + (size_t)bg2 * 1280 + idx, red[idx]);
    }
  }
}

// ---------------------------------------------------------------------------
extern "C" void kernel_launch(void* const* d_in, const int* in_sizes, int n_in,
                              void* d_out, int out_size, void* d_ws, size_t ws_size,
                              hipStream_t stream) {
  const float* x    = (const float*)d_in[0];
  const float* mask = (const float*)d_in[1];
  const float* thr  = (const float*)d_in[2];
  const float* lo   = (const float*)d_in[3];
  const float* W1   = (const float*)d_in[4];
  const float* b1   = (const float*)d_in[5];
  const float* W2   = (const float*)d_in[6];
  const float* b2   = (const float*)d_in[7];
  float* out = (float*)d_out;
  float* ws  = (float*)d_ws;

  __half*         attnB = (__half*)ws;
  unsigned int*   LPb   = (unsigned int*)(ws + OFF_LPB);
  unsigned short* xbf   = (unsigned short*)(ws + OFF_XBF);
  unsigned short* mbf   = (unsigned short*)(ws + OFF_MBF);

  prep_kernel<<<708, 64, 0, stream>>>(x, mask, lo, W1, b1, W2, b2,
                                      attnB, LPb, xbf, mbf, out);
  main_kernel<<<2048, 256, 0, stream>>>(xbf, mbf, thr, attnB, LPb, out);
}

// Round 11
// 155.666 us; speedup vs baseline: 5.9818x; 1.0677x over previous
//
#include <hip/hip_runtime.h>
#include <hip/hip_bf16.h>
#include <hip/hip_fp16.h>

// Problem: B=8192, T=128, D=7, I=128, C=10, H=64, L=128
// R25 = R24 grid/occupancy (2048 blocks, 32 waves/CU) with the atomic
// epilogue replaced by contention-free partial writes + reduce kernel.
// R24 PMC verdict: atomics were the wall (2.6M atomicAdd -> WRITE 186MB,
// FETCH 81MB, 2.9TB/s line-thrash at the coherence point; VALU 12.7%).
// Each (bg2,tg8) block now owns partial slice (tg8*64+bg2)*1280 (float4
// streams, no RMW); reduce: out = sum over 32 bands (10.5MB, L3-resident).
// ws layout (float slots):
//   attnB fp16 [8192][128] off 0        (524288)
//   LPb   uint4 compact    off 524288   (81920)   [t][s][n<10][hf]
//   xbf   bf16 [8192][128] off 606208   (524288)
//   mbf   bf16 [896][128]  off 1130496  (57344)
//   partial f32 [32][81920] off 1187840 (2621440)

#define BB 8192
#define TT 128
#define II 128
#define CC 10
#define HH 64

#define OFF_LPB 524288
#define OFF_XBF 606208
#define OFF_MBF 1130496
#define OFF_PT  1187840

typedef __attribute__((ext_vector_type(8))) short short8;
typedef __attribute__((ext_vector_type(16))) float floatx16;

static __device__ inline unsigned int pkbf(float lo, float hi) {
  __hip_bfloat162 h = __float22bfloat162_rn(make_float2(lo, hi));
  unsigned int u;
  __builtin_memcpy(&u, &h, 4);
  return u;
}

static __device__ inline unsigned int pkh(float lo, float hi) {
  __half2 h = __float22half2_rn(make_float2(lo, hi));
  unsigned int u;
  __builtin_memcpy(&u, &h, 4);
  return u;
}

static __device__ inline short8 cvt8(float4 a, float4 b) {
  union { short8 v; unsigned int u[4]; } r;
  r.u[0] = pkbf(a.x, a.y);
  r.u[1] = pkbf(a.z, a.w);
  r.u[2] = pkbf(b.x, b.y);
  r.u[3] = pkbf(b.z, b.w);
  return r.v;
}

// ---- prep: 668 blocks x 64 thr (R19-verified; zero-out duty removed) -------
// [0,256): attn, 32 rows/block (one wave)
// [256,384): leaf softmax, 1 tree/block
// [384,640): x f32->bf16, 4096 elems/block
// [640,668): mask f32->bf16, 4096 elems/block
__global__ __launch_bounds__(64) void prep_kernel(
    const float* __restrict__ x, const float* __restrict__ mask,
    const float* __restrict__ lo,
    const float* __restrict__ W1, const float* __restrict__ b1,
    const float* __restrict__ W2, const float* __restrict__ b2,
    __half* __restrict__ attnB, unsigned int* __restrict__ lpbG,
    unsigned short* __restrict__ xbf, unsigned short* __restrict__ mbf) {
  __shared__ __align__(16) char smem_raw[6144];
  const int blk = blockIdx.x;
  const int lane = threadIdx.x;           // 0..63 (one wave)
  const int half = lane >> 5, l31 = lane & 31;

  if (blk < 256) {
    // ---------------- attn: 32 rows, one wave -------------------------------
    const int b0 = blk * 32;

    short8 axf[8];
    const float* xrow = x + (size_t)(b0 + l31) * II + half * 8;
#pragma unroll
    for (int s = 0; s < 8; ++s)
      axf[s] = cvt8(*(const float4*)(xrow + s * 16),
                    *(const float4*)(xrow + s * 16 + 4));

    floatx16 acch[2];
#pragma unroll
    for (int i = 0; i < 16; ++i) { acch[0][i] = 0.f; acch[1][i] = 0.f; }
#pragma unroll
    for (int s = 0; s < 8; ++s) {
#pragma unroll
      for (int tile = 0; tile < 2; ++tile) {
        union { short8 v; unsigned int u[4]; } wf;
#pragma unroll
        for (int jp = 0; jp < 4; ++jp) {
          int k0 = s * 16 + half * 8 + jp * 2;
          float f0 = W1[(size_t)k0 * HH + tile * 32 + l31];
          float f1 = W1[(size_t)(k0 + 1) * HH + tile * 32 + l31];
          wf.u[jp] = pkbf(f0, f1);
        }
        acch[tile] = __builtin_amdgcn_mfma_f32_32x32x16_bf16(
            axf[s], wf.v, acch[tile], 0, 0, 0);
      }
    }
    __hip_bfloat16* hids = (__hip_bfloat16*)smem_raw;   // [32][72]
#pragma unroll
    for (int tile = 0; tile < 2; ++tile) {
      float bh = b1[tile * 32 + l31];
#pragma unroll
      for (int r = 0; r < 16; ++r) {
        int row = (r & 3) + 8 * (r >> 2) + 4 * half;
        hids[row * 72 + tile * 32 + l31] =
            __float2bfloat16(fmaxf(acch[tile][r] + bh, 0.f));
      }
    }
    __syncthreads();

    short8 ahf[4];
#pragma unroll
    for (int s = 0; s < 4; ++s)
      ahf[s] = *(const short8*)(hids + l31 * 72 + s * 16 + half * 8);

    floatx16 accl[4];
#pragma unroll
    for (int tile = 0; tile < 4; ++tile) {
#pragma unroll
      for (int i = 0; i < 16; ++i) accl[tile][i] = 0.f;
#pragma unroll
      for (int s = 0; s < 4; ++s) {
        union { short8 v; unsigned int u[4]; } wf;
#pragma unroll
        for (int jp = 0; jp < 4; ++jp) {
          int k0 = s * 16 + half * 8 + jp * 2;
          float f0 = W2[(size_t)k0 * TT + tile * 32 + l31];
          float f1 = W2[(size_t)(k0 + 1) * TT + tile * 32 + l31];
          wf.u[jp] = pkbf(f0, f1);
        }
        accl[tile] = __builtin_amdgcn_mfma_f32_32x32x16_bf16(
            ahf[s], wf.v, accl[tile], 0, 0, 0);
      }
      float bt = b2[tile * 32 + l31];
#pragma unroll
      for (int i = 0; i < 16; ++i) accl[tile][i] += bt;
    }

    float mrow[16];
#pragma unroll
    for (int r = 0; r < 16; ++r)
      mrow[r] = fmaxf(fmaxf(accl[0][r], accl[1][r]),
                      fmaxf(accl[2][r], accl[3][r]));
#pragma unroll
    for (int msk = 1; msk <= 16; msk <<= 1)
#pragma unroll
      for (int r = 0; r < 16; ++r)
        mrow[r] = fmaxf(mrow[r], __shfl_xor(mrow[r], msk, 64));
    float srow[16];
#pragma unroll
    for (int r = 0; r < 16; ++r) srow[r] = 0.f;
#pragma unroll
    for (int tile = 0; tile < 4; ++tile)
#pragma unroll
      for (int r = 0; r < 16; ++r) {
        float e = __expf(accl[tile][r] - mrow[r]);
        accl[tile][r] = e;
        srow[r] += e;
      }
#pragma unroll
    for (int msk = 1; msk <= 16; msk <<= 1)
#pragma unroll
      for (int r = 0; r < 16; ++r)
        srow[r] += __shfl_xor(srow[r], msk, 64);
#pragma unroll
    for (int r = 0; r < 16; ++r) srow[r] = 1.f / srow[r];

#pragma unroll
    for (int tile = 0; tile < 4; ++tile)
#pragma unroll
      for (int r = 0; r < 16; ++r) {
        int row = (r & 3) + 8 * (r >> 2) + 4 * half;
        attnB[(size_t)(b0 + row) * TT + tile * 32 + l31] =
            __float2half(accl[tile][r] * srow[r]);
      }

  } else if (blk < 384) {
    // ------- leaf softmax (1 tree) -> COMPACT fp16 B-frags ------------------
    float* lps = (float*)smem_raw;   // [128][12] f32 = 6144 B
    const int t0 = blk - 256;
#pragma unroll
    for (int rr = 0; rr < 2; ++rr) {
      int l = lane * 2 + rr;         // 0..127
      const float* row = lo + ((size_t)t0 * 128 + l) * CC;
      float v[CC];
      float m = -1e30f;
#pragma unroll
      for (int c = 0; c < CC; ++c) { v[c] = row[c]; m = fmaxf(m, v[c]); }
      float s = 0.f;
#pragma unroll
      for (int c = 0; c < CC; ++c) { v[c] = __expf(v[c] - m); s += v[c]; }
      float inv = 1.f / s;
      float* o = lps + l * 12;
#pragma unroll
      for (int c = 0; c < CC; ++c) o[c] = v[c] * inv;
    }
    __syncthreads();

    // layout: idx = tree*160 + s*20 + n*2 + hf  (uint4)
#pragma unroll
    for (int jj = 0; jj < 3; ++jj) {
      int idx = jj * 64 + lane;      // 0..191
      if (idx < 160) {
        int s = idx / 20, e = idx - s * 20;
        int n = e >> 1, hf = e & 1;
        unsigned int wd[4];
#pragma unroll
        for (int jp = 0; jp < 4; ++jp) {
          int l0 = s * 16 + hf * 8 + jp * 2;
          float f0 = lps[l0 * 12 + n];
          float f1 = lps[(l0 + 1) * 12 + n];
          wd[jp] = pkh(f0, f1);
        }
        ((uint4*)lpbG)[(size_t)t0 * 160 + idx] =
            make_uint4(wd[0], wd[1], wd[2], wd[3]);
      }
    }
  } else {
    // ------------- f32 -> bf16: x (256 blocks) / mask (28 blocks) -----------
    const float* src;
    unsigned short* dst;
    size_t base;
    if (blk < 640) { src = x;    dst = xbf; base = (size_t)(blk - 384) * 4096; }
    else           { src = mask; dst = mbf; base = (size_t)(blk - 640) * 4096; }
#pragma unroll
    for (int j = 0; j < 8; ++j) {
      size_t e = base + (size_t)j * 512 + (size_t)lane * 8;
      float4 a = *(const float4*)(src + e);
      float4 b = *(const float4*)(src + e + 4);
      *(short8*)(dst + e) = cvt8(a, b);
    }
  }
}

// -------- main: 2048 blocks = (tg8 0..31 fast) x (bg2 0..63), 4 trees -------
// Per wave: 32 rows x 4 trees. LDS 8KB. launch_bounds(256,8): 32 waves/CU
// (R24-verified: occ 63%, VGPR 32). Epilogue: private partial slice, float4
// streams, NO atomics (R24's 186MB write-thrash removed).
__global__ __launch_bounds__(256, 8) void main_kernel(
    const unsigned short* __restrict__ xbf, const unsigned short* __restrict__ mbf,
    const float* __restrict__ thr, const __half* __restrict__ attnB,
    const unsigned int* __restrict__ lpbG, float* __restrict__ partial) {
  __shared__ __align__(16) char smem_raw[8192];
  const int tid = threadIdx.x;
  const int wv = tid >> 6, lane = tid & 63;
  const int half = lane >> 5, l31 = lane & 31;
  const int phys = blockIdx.x;
  const int tg8 = phys & 31;                      // 0..31: trees tg8*4..+4
  const int bg2 = phys >> 5;                      // 0..63: rows bg2*128..+128
  const int bl = wv * 32 + l31;                   // own local row 0..127

  __half* zsl = (__half*)smem_raw;                // [4 tree][128 row][8]

  // early load: attn vector for own row (hides under phase 1)
  // attnB row = 128 halves = 32 uint2 (uint2 = 4 halves); group tg8 -> +tg8.
  __half av[4];
  *(uint2*)av = ((const uint2*)attnB)[(size_t)(bg2 * 128 + bl) * 32 + tg8];

  // ==================== Phase 1: zs -> LDS (per-wave rows) ==================
  {
    const int m0 = tg8 * 28;
    short8 xf[8];
    const unsigned short* xr = xbf + (size_t)(bg2 * 128 + bl) * II + half * 8;
#pragma unroll
    for (int s = 0; s < 8; ++s) xf[s] = *(const short8*)(xr + s * 16);

    int mr = m0 + l31; if (mr > 895) mr = 895;   // A-pad clamp (tg8=31 only)
    const unsigned short* mrow = mbf + (size_t)mr * II + half * 8;

    floatx16 acc;
#pragma unroll
    for (int i = 0; i < 16; ++i) acc[i] = 0.f;
#pragma unroll
    for (int s = 0; s < 8; ++s) {
      short8 af = *(const short8*)(mrow + s * 16);
      acc = __builtin_amdgcn_mfma_f32_32x32x16_bf16(af, xf[s], acc, 0, 0, 0);
    }

#pragma unroll
    for (int r = 0; r < 16; ++r) {
      int row = (r & 3) + 8 * (r >> 2) + 4 * half;   // m-local 0..31
      if (row < 28) {                                // m0+row <= 895 always
        int tl = row / 7;
        int d = row - tl * 7;
        float z = acc[r] - thr[m0 + row];
        float o = 0.5f * (z / (1.f + fabsf(z)) + 1.f);
        zsl[((tl * 128) + bl) * 8 + d] = __float2half(o);
      }
    }
  }
  // NO barrier: each wave reads only the zsl rows it wrote

  // ==================== Phase 2: contraction (4 trees) ======================
  {
    const uint4* zsl4 = (const uint4*)smem_raw;
    const uint4* lpt = (const uint4*)lpbG + (size_t)tg8 * 640;

    floatx16 acc;
#pragma unroll
    for (int i = 0; i < 16; ++i) acc[i] = 0.f;

    auto dostep = [&](int it, const uint4* bf) {
      uint4 sv = zsl4[it * 128 + bl];
      const __half* sh = (const __half*)&sv;
      float s0 = __half2float(sh[0]), s1 = __half2float(sh[1]);
      float s2 = __half2float(sh[2]), s3 = __half2float(sh[3]);
      float s4 = __half2float(sh[4]), s5 = __half2float(sh[5]);
      float s6 = __half2float(sh[6]);
      float A  = __half2float(av[it]);

      float s0c = 1.f - s0, s1c = 1.f - s1, s2c = 1.f - s2;
      float t0 = s0 * s1, t1 = s0c * s1, t2 = s0 * s1c, t3 = s0c * s1c;
      float pl[8];
      pl[0] = t0 * s2;  pl[1] = t1 * s2;  pl[2] = t2 * s2;  pl[3] = t3 * s2;
      pl[4] = t0 * s2c; pl[5] = t1 * s2c; pl[6] = t2 * s2c; pl[7] = t3 * s2c;
      float sel3 = half ? (1.f - s3) : s3;
      float Af = A * sel3;
      float s4c = 1.f - s4, s5c = 1.f - s5;
      float as6 = Af * s6, as6c = Af * (1.f - s6);
      float u0 = s4 * s5, u1 = s4c * s5, u2 = s4 * s5c, u3 = s4c * s5c;
      float wv8[8];
      wv8[0] = u0 * as6;  wv8[1] = u1 * as6;
      wv8[2] = u2 * as6;  wv8[3] = u3 * as6;
      wv8[4] = u0 * as6c; wv8[5] = u1 * as6c;
      wv8[6] = u2 * as6c; wv8[7] = u3 * as6c;
      __half2 pl2[4];
#pragma unroll
      for (int jp = 0; jp < 4; ++jp)
        pl2[jp] = __float22half2_rn(make_float2(pl[jp * 2], pl[jp * 2 + 1]));

#pragma unroll
      for (int s = 0; s < 8; ++s) {
        union { short8 v; __half2 h[4]; } a0;
        __half2 w2 = __half2half2(__float2half(wv8[s]));
#pragma unroll
        for (int jp = 0; jp < 4; ++jp) a0.h[jp] = __hmul2(pl2[jp], w2);
        acc = __builtin_amdgcn_mfma_f32_32x32x16_f16(
            a0.v, *(const short8*)&bf[s], acc, 0, 0, 0);
      }
    };

#define PF(dst, itn)                                                       \
  _Pragma("unroll") for (int s = 0; s < 8; ++s)                            \
      dst[s] = (l31 < CC) ? lpt[((itn) * 8 + s) * 20 + l31 * 2 + half]     \
                          : make_uint4(0u, 0u, 0u, 0u);

    uint4 bf0[8], bf1[8];
    PF(bf0, 0)
#pragma unroll
    for (int ith = 0; ith < 2; ++ith) {
      const int it = ith * 2;
      PF(bf1, it + 1)            // issue next-tree loads...
      dostep(it, bf0);           // ...hidden under this tree's VALU+MFMA
      if (ith < 1) { PF(bf0, it + 2) }
      dostep(it + 1, bf1);
    }
#undef PF

    // ---- epilogue: red overlays zsl -> PRIVATE partial slice (no atomics) --
    __syncthreads();   // every wave done reading its zsl before overlay write
    float* red = (float*)smem_raw;   // [128][10] f32 = 5120 B
    if (l31 < CC) {
#pragma unroll
      for (int r = 0; r < 16; ++r) {
        int row = (r & 3) + 8 * (r >> 2) + 4 * half;
        red[(wv * 32 + row) * 10 + l31] = acc[r];
      }
    }
    __syncthreads();
    const float4* r4 = (const float4*)red;            // 320 float4
    float4* p4 = (float4*)(partial + ((size_t)tg8 * 64 + bg2) * 1280);
    p4[tid] = r4[tid];
    if (tid < 64) p4[256 + tid] = r4[256 + tid];
  }
}

// ---- reduce: out[81920] = sum over 32 bands of partial (L3-resident) -------
__global__ __launch_bounds__(256) void reduce_kernel(
    const float* __restrict__ partial, float* __restrict__ out) {
  const int i = blockIdx.x * 256 + threadIdx.x;   // 0..20479 float4
  float4 s = make_float4(0.f, 0.f, 0.f, 0.f);
#pragma unroll
  for (int b = 0; b < 32; ++b) {
    float4 v = ((const float4*)partial)[(size_t)b * 20480 + i];
    s.x += v.x; s.y += v.y; s.z += v.z; s.w += v.w;
  }
  ((float4*)out)[i] = s;
}

// ---------------------------------------------------------------------------
extern "C" void kernel_launch(void* const* d_in, const int* in_sizes, int n_in,
                              void* d_out, int out_size, void* d_ws, size_t ws_size,
                              hipStream_t stream) {
  const float* x    = (const float*)d_in[0];
  const float* mask = (const float*)d_in[1];
  const float* thr  = (const float*)d_in[2];
  const float* lo   = (const float*)d_in[3];
  const float* W1   = (const float*)d_in[4];
  const float* b1   = (const float*)d_in[5];
  const float* W2   = (const float*)d_in[6];
  const float* b2   = (const float*)d_in[7];
  float* out = (float*)d_out;
  float* ws  = (float*)d_ws;

  __half*         attnB   = (__half*)ws;
  unsigned int*   LPb     = (unsigned int*)(ws + OFF_LPB);
  unsigned short* xbf     = (unsigned short*)(ws + OFF_XBF);
  unsigned short* mbf     = (unsigned short*)(ws + OFF_MBF);
  float*          partial = ws + OFF_PT;

  prep_kernel<<<668, 64, 0, stream>>>(x, mask, lo, W1, b1, W2, b2,
                                      attnB, LPb, xbf, mbf);
  main_kernel<<<2048, 256, 0, stream>>>(xbf, mbf, thr, attnB, LPb, partial);
  reduce_kernel<<<80, 256, 0, stream>>>(partial, out);
}

// Round 12
// 109.995 us; speedup vs baseline: 8.4655x; 1.4152x over previous
//
#include <hip/hip_runtime.h>
#include <hip/hip_bf16.h>
#include <hip/hip_fp16.h>

// Problem: B=8192, T=128, D=7, I=128, C=10, H=64, L=128
// R26: R25 skeleton with the REAL bug fixed. R25 PMC: WRITE 167MB with no
// atomics + VGPR_Count=32 => scratch spill from launch_bounds(256,8)'s
// 64-VGPR cap vs ~100-reg live set (bf0/bf1 double buffer). R24's "atomic
// thrash" diagnosis was wrong -- same spill signature there.
// Fix: single bf[8] buffer (live ~70) + launch_bounds(256,6) (85 VGPR cap,
// 24 waves/CU). Latency hidden by TLP, not spilled ILP.
// main: 2048 blocks = (tg8 0..31 fast) x (bg2 0..63), 4 trees/block;
// epilogue: private partial slice (no atomics) + reduce kernel.
// ws layout (float slots):
//   attnB fp16 [8192][128] off 0        (524288)
//   LPb   uint4 compact    off 524288   (81920)   [t][s][n<10][hf]
//   xbf   bf16 [8192][128] off 606208   (524288)
//   mbf   bf16 [896][128]  off 1130496  (57344)
//   partial f32 [32][81920] off 1187840 (2621440)

#define BB 8192
#define TT 128
#define II 128
#define CC 10
#define HH 64

#define OFF_LPB 524288
#define OFF_XBF 606208
#define OFF_MBF 1130496
#define OFF_PT  1187840

typedef __attribute__((ext_vector_type(8))) short short8;
typedef __attribute__((ext_vector_type(16))) float floatx16;

static __device__ inline unsigned int pkbf(float lo, float hi) {
  __hip_bfloat162 h = __float22bfloat162_rn(make_float2(lo, hi));
  unsigned int u;
  __builtin_memcpy(&u, &h, 4);
  return u;
}

static __device__ inline unsigned int pkh(float lo, float hi) {
  __half2 h = __float22half2_rn(make_float2(lo, hi));
  unsigned int u;
  __builtin_memcpy(&u, &h, 4);
  return u;
}

static __device__ inline short8 cvt8(float4 a, float4 b) {
  union { short8 v; unsigned int u[4]; } r;
  r.u[0] = pkbf(a.x, a.y);
  r.u[1] = pkbf(a.z, a.w);
  r.u[2] = pkbf(b.x, b.y);
  r.u[3] = pkbf(b.z, b.w);
  return r.v;
}

// ---- prep: 668 blocks x 64 thr (R19-verified) ------------------------------
// [0,256): attn | [256,384): leaf softmax | [384,640): x cvt | [640,668): mask
__global__ __launch_bounds__(64) void prep_kernel(
    const float* __restrict__ x, const float* __restrict__ mask,
    const float* __restrict__ lo,
    const float* __restrict__ W1, const float* __restrict__ b1,
    const float* __restrict__ W2, const float* __restrict__ b2,
    __half* __restrict__ attnB, unsigned int* __restrict__ lpbG,
    unsigned short* __restrict__ xbf, unsigned short* __restrict__ mbf) {
  __shared__ __align__(16) char smem_raw[6144];
  const int blk = blockIdx.x;
  const int lane = threadIdx.x;           // 0..63 (one wave)
  const int half = lane >> 5, l31 = lane & 31;

  if (blk < 256) {
    // ---------------- attn: 32 rows, one wave -------------------------------
    const int b0 = blk * 32;

    short8 axf[8];
    const float* xrow = x + (size_t)(b0 + l31) * II + half * 8;
#pragma unroll
    for (int s = 0; s < 8; ++s)
      axf[s] = cvt8(*(const float4*)(xrow + s * 16),
                    *(const float4*)(xrow + s * 16 + 4));

    floatx16 acch[2];
#pragma unroll
    for (int i = 0; i < 16; ++i) { acch[0][i] = 0.f; acch[1][i] = 0.f; }
#pragma unroll
    for (int s = 0; s < 8; ++s) {
#pragma unroll
      for (int tile = 0; tile < 2; ++tile) {
        union { short8 v; unsigned int u[4]; } wf;
#pragma unroll
        for (int jp = 0; jp < 4; ++jp) {
          int k0 = s * 16 + half * 8 + jp * 2;
          float f0 = W1[(size_t)k0 * HH + tile * 32 + l31];
          float f1 = W1[(size_t)(k0 + 1) * HH + tile * 32 + l31];
          wf.u[jp] = pkbf(f0, f1);
        }
        acch[tile] = __builtin_amdgcn_mfma_f32_32x32x16_bf16(
            axf[s], wf.v, acch[tile], 0, 0, 0);
      }
    }
    __hip_bfloat16* hids = (__hip_bfloat16*)smem_raw;   // [32][72]
#pragma unroll
    for (int tile = 0; tile < 2; ++tile) {
      float bh = b1[tile * 32 + l31];
#pragma unroll
      for (int r = 0; r < 16; ++r) {
        int row = (r & 3) + 8 * (r >> 2) + 4 * half;
        hids[row * 72 + tile * 32 + l31] =
            __float2bfloat16(fmaxf(acch[tile][r] + bh, 0.f));
      }
    }
    __syncthreads();

    short8 ahf[4];
#pragma unroll
    for (int s = 0; s < 4; ++s)
      ahf[s] = *(const short8*)(hids + l31 * 72 + s * 16 + half * 8);

    floatx16 accl[4];
#pragma unroll
    for (int tile = 0; tile < 4; ++tile) {
#pragma unroll
      for (int i = 0; i < 16; ++i) accl[tile][i] = 0.f;
#pragma unroll
      for (int s = 0; s < 4; ++s) {
        union { short8 v; unsigned int u[4]; } wf;
#pragma unroll
        for (int jp = 0; jp < 4; ++jp) {
          int k0 = s * 16 + half * 8 + jp * 2;
          float f0 = W2[(size_t)k0 * TT + tile * 32 + l31];
          float f1 = W2[(size_t)(k0 + 1) * TT + tile * 32 + l31];
          wf.u[jp] = pkbf(f0, f1);
        }
        accl[tile] = __builtin_amdgcn_mfma_f32_32x32x16_bf16(
            ahf[s], wf.v, accl[tile], 0, 0, 0);
      }
      float bt = b2[tile * 32 + l31];
#pragma unroll
      for (int i = 0; i < 16; ++i) accl[tile][i] += bt;
    }

    float mrow[16];
#pragma unroll
    for (int r = 0; r < 16; ++r)
      mrow[r] = fmaxf(fmaxf(accl[0][r], accl[1][r]),
                      fmaxf(accl[2][r], accl[3][r]));
#pragma unroll
    for (int msk = 1; msk <= 16; msk <<= 1)
#pragma unroll
      for (int r = 0; r < 16; ++r)
        mrow[r] = fmaxf(mrow[r], __shfl_xor(mrow[r], msk, 64));
    float srow[16];
#pragma unroll
    for (int r = 0; r < 16; ++r) srow[r] = 0.f;
#pragma unroll
    for (int tile = 0; tile < 4; ++tile)
#pragma unroll
      for (int r = 0; r < 16; ++r) {
        float e = __expf(accl[tile][r] - mrow[r]);
        accl[tile][r] = e;
        srow[r] += e;
      }
#pragma unroll
    for (int msk = 1; msk <= 16; msk <<= 1)
#pragma unroll
      for (int r = 0; r < 16; ++r)
        srow[r] += __shfl_xor(srow[r], msk, 64);
#pragma unroll
    for (int r = 0; r < 16; ++r) srow[r] = 1.f / srow[r];

#pragma unroll
    for (int tile = 0; tile < 4; ++tile)
#pragma unroll
      for (int r = 0; r < 16; ++r) {
        int row = (r & 3) + 8 * (r >> 2) + 4 * half;
        attnB[(size_t)(b0 + row) * TT + tile * 32 + l31] =
            __float2half(accl[tile][r] * srow[r]);
      }

  } else if (blk < 384) {
    // ------- leaf softmax (1 tree) -> COMPACT fp16 B-frags ------------------
    float* lps = (float*)smem_raw;   // [128][12] f32 = 6144 B
    const int t0 = blk - 256;
#pragma unroll
    for (int rr = 0; rr < 2; ++rr) {
      int l = lane * 2 + rr;         // 0..127
      const float* row = lo + ((size_t)t0 * 128 + l) * CC;
      float v[CC];
      float m = -1e30f;
#pragma unroll
      for (int c = 0; c < CC; ++c) { v[c] = row[c]; m = fmaxf(m, v[c]); }
      float s = 0.f;
#pragma unroll
      for (int c = 0; c < CC; ++c) { v[c] = __expf(v[c] - m); s += v[c]; }
      float inv = 1.f / s;
      float* o = lps + l * 12;
#pragma unroll
      for (int c = 0; c < CC; ++c) o[c] = v[c] * inv;
    }
    __syncthreads();

    // layout: idx = tree*160 + s*20 + n*2 + hf  (uint4)
#pragma unroll
    for (int jj = 0; jj < 3; ++jj) {
      int idx = jj * 64 + lane;      // 0..191
      if (idx < 160) {
        int s = idx / 20, e = idx - s * 20;
        int n = e >> 1, hf = e & 1;
        unsigned int wd[4];
#pragma unroll
        for (int jp = 0; jp < 4; ++jp) {
          int l0 = s * 16 + hf * 8 + jp * 2;
          float f0 = lps[l0 * 12 + n];
          float f1 = lps[(l0 + 1) * 12 + n];
          wd[jp] = pkh(f0, f1);
        }
        ((uint4*)lpbG)[(size_t)t0 * 160 + idx] =
            make_uint4(wd[0], wd[1], wd[2], wd[3]);
      }
    }
  } else {
    // ------------- f32 -> bf16: x (256 blocks) / mask (28 blocks) -----------
    const float* src;
    unsigned short* dst;
    size_t base;
    if (blk < 640) { src = x;    dst = xbf; base = (size_t)(blk - 384) * 4096; }
    else           { src = mask; dst = mbf; base = (size_t)(blk - 640) * 4096; }
#pragma unroll
    for (int j = 0; j < 8; ++j) {
      size_t e = base + (size_t)j * 512 + (size_t)lane * 8;
      float4 a = *(const float4*)(src + e);
      float4 b = *(const float4*)(src + e + 4);
      *(short8*)(dst + e) = cvt8(a, b);
    }
  }
}

// -------- main: 2048 blocks = (tg8 0..31 fast) x (bg2 0..63), 4 trees -------
// Single bf[8] buffer; launch_bounds(256,6): 85 VGPR cap (live ~70, NO spill),
// 6 blocks/CU = 24 waves/CU. LDS 8KB. Epilogue: private partial, no atomics.
__global__ __launch_bounds__(256, 6) void main_kernel(
    const unsigned short* __restrict__ xbf, const unsigned short* __restrict__ mbf,
    const float* __restrict__ thr, const __half* __restrict__ attnB,
    const unsigned int* __restrict__ lpbG, float* __restrict__ partial) {
  __shared__ __align__(16) char smem_raw[8192];
  const int tid = threadIdx.x;
  const int wv = tid >> 6, lane = tid & 63;
  const int half = lane >> 5, l31 = lane & 31;
  const int phys = blockIdx.x;
  const int tg8 = phys & 31;                      // 0..31: trees tg8*4..+4
  const int bg2 = phys >> 5;                      // 0..63: rows bg2*128..+128
  const int bl = wv * 32 + l31;                   // own local row 0..127

  __half* zsl = (__half*)smem_raw;                // [4 tree][128 row][8]

  // early load: attn vector for own row (hides under phase 1)
  // attnB row = 128 halves = 32 uint2; group tg8 -> +tg8 (R24-verified).
  __half av[4];
  *(uint2*)av = ((const uint2*)attnB)[(size_t)(bg2 * 128 + bl) * 32 + tg8];

  // ==================== Phase 1: zs -> LDS (per-wave rows) ==================
  {
    const int m0 = tg8 * 28;
    short8 xf[8];
    const unsigned short* xr = xbf + (size_t)(bg2 * 128 + bl) * II + half * 8;
#pragma unroll
    for (int s = 0; s < 8; ++s) xf[s] = *(const short8*)(xr + s * 16);

    int mr = m0 + l31; if (mr > 895) mr = 895;   // A-pad clamp (tg8=31 only)
    const unsigned short* mrow = mbf + (size_t)mr * II + half * 8;

    floatx16 acc;
#pragma unroll
    for (int i = 0; i < 16; ++i) acc[i] = 0.f;
#pragma unroll
    for (int s = 0; s < 8; ++s) {
      short8 af = *(const short8*)(mrow + s * 16);
      acc = __builtin_amdgcn_mfma_f32_32x32x16_bf16(af, xf[s], acc, 0, 0, 0);
    }

#pragma unroll
    for (int r = 0; r < 16; ++r) {
      int row = (r & 3) + 8 * (r >> 2) + 4 * half;   // m-local 0..31
      if (row < 28) {                                // m0+row <= 895 always
        int tl = row / 7;
        int d = row - tl * 7;
        float z = acc[r] - thr[m0 + row];
        float o = 0.5f * (z / (1.f + fabsf(z)) + 1.f);
        zsl[((tl * 128) + bl) * 8 + d] = __float2half(o);
      }
    }
  }
  // NO barrier: each wave reads only the zsl rows it wrote

  // ==================== Phase 2: contraction (4 trees) ======================
  {
    const uint4* zsl4 = (const uint4*)smem_raw;
    const uint4* lpt = (const uint4*)lpbG + (size_t)tg8 * 640;

    floatx16 acc;
#pragma unroll
    for (int i = 0; i < 16; ++i) acc[i] = 0.f;

#pragma unroll
    for (int it = 0; it < 4; ++it) {
      uint4 bf[8];   // single buffer: live set fits the 85-VGPR cap
#pragma unroll
      for (int s = 0; s < 8; ++s)
        bf[s] = (l31 < CC) ? lpt[(it * 8 + s) * 20 + l31 * 2 + half]
                           : make_uint4(0u, 0u, 0u, 0u);
      uint4 sv = zsl4[it * 128 + bl];

      const __half* sh = (const __half*)&sv;
      float s0 = __half2float(sh[0]), s1 = __half2float(sh[1]);
      float s2 = __half2float(sh[2]), s3 = __half2float(sh[3]);
      float s4 = __half2float(sh[4]), s5 = __half2float(sh[5]);
      float s6 = __half2float(sh[6]);
      float A  = __half2float(av[it]);

      float s0c = 1.f - s0, s1c = 1.f - s1, s2c = 1.f - s2;
      float t0 = s0 * s1, t1 = s0c * s1, t2 = s0 * s1c, t3 = s0c * s1c;
      float pl[8];
      pl[0] = t0 * s2;  pl[1] = t1 * s2;  pl[2] = t2 * s2;  pl[3] = t3 * s2;
      pl[4] = t0 * s2c; pl[5] = t1 * s2c; pl[6] = t2 * s2c; pl[7] = t3 * s2c;
      float sel3 = half ? (1.f - s3) : s3;
      float Af = A * sel3;
      float s4c = 1.f - s4, s5c = 1.f - s5;
      float as6 = Af * s6, as6c = Af * (1.f - s6);
      float u0 = s4 * s5, u1 = s4c * s5, u2 = s4 * s5c, u3 = s4c * s5c;
      float wv8[8];
      wv8[0] = u0 * as6;  wv8[1] = u1 * as6;
      wv8[2] = u2 * as6;  wv8[3] = u3 * as6;
      wv8[4] = u0 * as6c; wv8[5] = u1 * as6c;
      wv8[6] = u2 * as6c; wv8[7] = u3 * as6c;
      __half2 pl2[4];
#pragma unroll
      for (int jp = 0; jp < 4; ++jp)
        pl2[jp] = __float22half2_rn(make_float2(pl[jp * 2], pl[jp * 2 + 1]));

#pragma unroll
      for (int s = 0; s < 8; ++s) {
        union { short8 v; __half2 h[4]; } a0;
        __half2 w2 = __half2half2(__float2half(wv8[s]));
#pragma unroll
        for (int jp = 0; jp < 4; ++jp) a0.h[jp] = __hmul2(pl2[jp], w2);
        acc = __builtin_amdgcn_mfma_f32_32x32x16_f16(
            a0.v, *(const short8*)&bf[s], acc, 0, 0, 0);
      }
    }

    // ---- epilogue: red overlays zsl -> PRIVATE partial slice (no atomics) --
    __syncthreads();   // every wave done reading its zsl before overlay write
    float* red = (float*)smem_raw;   // [128][10] f32 = 5120 B
    if (l31 < CC) {
#pragma unroll
      for (int r = 0; r < 16; ++r) {
        int row = (r & 3) + 8 * (r >> 2) + 4 * half;
        red[(wv * 32 + row) * 10 + l31] = acc[r];
      }
    }
    __syncthreads();
    const float4* r4 = (const float4*)red;            // 320 float4
    float4* p4 = (float4*)(partial + ((size_t)tg8 * 64 + bg2) * 1280);
    p4[tid] = r4[tid];
    if (tid < 64) p4[256 + tid] = r4[256 + tid];
  }
}

// ---- reduce: out[81920] = sum over 32 bands of partial (L3-resident) -------
__global__ __launch_bounds__(256) void reduce_kernel(
    const float* __restrict__ partial, float* __restrict__ out) {
  const int i = blockIdx.x * 256 + threadIdx.x;   // 0..20479 float4
  float4 s = make_float4(0.f, 0.f, 0.f, 0.f);
#pragma unroll
  for (int b = 0; b < 32; ++b) {
    float4 v = ((const float4*)partial)[(size_t)b * 20480 + i];
    s.x += v.x; s.y += v.y; s.z += v.z; s.w += v.w;
  }
  ((float4*)out)[i] = s;
}

// ---------------------------------------------------------------------------
extern "C" void kernel_launch(void* const* d_in, const int* in_sizes, int n_in,
                              void* d_out, int out_size, void* d_ws, size_t ws_size,
                              hipStream_t stream) {
  const float* x    = (const float*)d_in[0];
  const float* mask = (const float*)d_in[1];
  const float* thr  = (const float*)d_in[2];
  const float* lo   = (const float*)d_in[3];
  const float* W1   = (const float*)d_in[4];
  const float* b1   = (const float*)d_in[5];
  const float* W2   = (const float*)d_in[6];
  const float* b2   = (const float*)d_in[7];
  float* out = (float*)d_out;
  float* ws  = (float*)d_ws;

  __half*         attnB   = (__half*)ws;
  unsigned int*   LPb     = (unsigned int*)(ws + OFF_LPB);
  unsigned short* xbf     = (unsigned short*)(ws + OFF_XBF);
  unsigned short* mbf     = (unsigned short*)(ws + OFF_MBF);
  float*          partial = ws + OFF_PT;

  prep_kernel<<<668, 64, 0, stream>>>(x, mask, lo, W1, b1, W2, b2,
                                      attnB, LPb, xbf, mbf);
  main_kernel<<<2048, 256, 0, stream>>>(xbf, mbf, thr, attnB, LPb, partial);
  reduce_kernel<<<80, 256, 0, stream>>>(partial, out);
}

// Round 13
// 106.115 us; speedup vs baseline: 8.7750x; 1.0366x over previous
//
#include <hip/hip_runtime.h>
#include <hip/hip_bf16.h>
#include <hip/hip_fp16.h>

// Problem: B=8192, T=128, D=7, I=128, C=10, H=64, L=128
// R27 = R26's no-spill main (2048 blk, 24 waves/CU, single bf[8], 85-VGPR
// budget) + R19's 2-launch shape (atomic epilogue, no reduce kernel; launch
// boundary ~5us each).  New: atomic-locality swizzle bg2=phys&63,
// tg8=phys>>6 -> all 32 blocks sharing an out-slice have phys==bg2 (mod 8)
// = SAME XCD: 32-way atomicAdd resolves in one L2 (no cross-XCD line
// ping-pong, R24's failure mode), and xbf row reads are L2-local too.
// Failure read: WRITE>100MB => within-XCD atomics thrash too; partial+reduce
// is mandatory and we're at the structural floor.
// ws layout (float slots):
//   attnB fp16 [8192][128] off 0        (524288)
//   LPb   uint4 compact    off 524288   (81920)   [t][s][n<10][hf]
//   xbf   bf16 [8192][128] off 606208   (524288)
//   mbf   bf16 [896][128]  off 1130496  (57344)

#define BB 8192
#define TT 128
#define II 128
#define CC 10
#define HH 64

#define OFF_LPB 524288
#define OFF_XBF 606208
#define OFF_MBF 1130496

typedef __attribute__((ext_vector_type(8))) short short8;
typedef __attribute__((ext_vector_type(16))) float floatx16;

static __device__ inline unsigned int pkbf(float lo, float hi) {
  __hip_bfloat162 h = __float22bfloat162_rn(make_float2(lo, hi));
  unsigned int u;
  __builtin_memcpy(&u, &h, 4);
  return u;
}

static __device__ inline unsigned int pkh(float lo, float hi) {
  __half2 h = __float22half2_rn(make_float2(lo, hi));
  unsigned int u;
  __builtin_memcpy(&u, &h, 4);
  return u;
}

static __device__ inline short8 cvt8(float4 a, float4 b) {
  union { short8 v; unsigned int u[4]; } r;
  r.u[0] = pkbf(a.x, a.y);
  r.u[1] = pkbf(a.z, a.w);
  r.u[2] = pkbf(b.x, b.y);
  r.u[3] = pkbf(b.z, b.w);
  return r.v;
}

// ---- prep: 708 blocks x 64 thr (R19-verified) ------------------------------
// [0,256): attn | [256,384): leaf softmax | [384,640): x cvt | [640,668): mask
// [668,708): zero out
__global__ __launch_bounds__(64) void prep_kernel(
    const float* __restrict__ x, const float* __restrict__ mask,
    const float* __restrict__ lo,
    const float* __restrict__ W1, const float* __restrict__ b1,
    const float* __restrict__ W2, const float* __restrict__ b2,
    __half* __restrict__ attnB, unsigned int* __restrict__ lpbG,
    unsigned short* __restrict__ xbf, unsigned short* __restrict__ mbf,
    float* __restrict__ out) {
  __shared__ __align__(16) char smem_raw[6144];
  const int blk = blockIdx.x;
  const int lane = threadIdx.x;           // 0..63 (one wave)
  const int half = lane >> 5, l31 = lane & 31;

  if (blk < 256) {
    // ---------------- attn: 32 rows, one wave -------------------------------
    const int b0 = blk * 32;

    short8 axf[8];
    const float* xrow = x + (size_t)(b0 + l31) * II + half * 8;
#pragma unroll
    for (int s = 0; s < 8; ++s)
      axf[s] = cvt8(*(const float4*)(xrow + s * 16),
                    *(const float4*)(xrow + s * 16 + 4));

    floatx16 acch[2];
#pragma unroll
    for (int i = 0; i < 16; ++i) { acch[0][i] = 0.f; acch[1][i] = 0.f; }
#pragma unroll
    for (int s = 0; s < 8; ++s) {
#pragma unroll
      for (int tile = 0; tile < 2; ++tile) {
        union { short8 v; unsigned int u[4]; } wf;
#pragma unroll
        for (int jp = 0; jp < 4; ++jp) {
          int k0 = s * 16 + half * 8 + jp * 2;
          float f0 = W1[(size_t)k0 * HH + tile * 32 + l31];
          float f1 = W1[(size_t)(k0 + 1) * HH + tile * 32 + l31];
          wf.u[jp] = pkbf(f0, f1);
        }
        acch[tile] = __builtin_amdgcn_mfma_f32_32x32x16_bf16(
            axf[s], wf.v, acch[tile], 0, 0, 0);
      }
    }
    __hip_bfloat16* hids = (__hip_bfloat16*)smem_raw;   // [32][72]
#pragma unroll
    for (int tile = 0; tile < 2; ++tile) {
      float bh = b1[tile * 32 + l31];
#pragma unroll
      for (int r = 0; r < 16; ++r) {
        int row = (r & 3) + 8 * (r >> 2) + 4 * half;
        hids[row * 72 + tile * 32 + l31] =
            __float2bfloat16(fmaxf(acch[tile][r] + bh, 0.f));
      }
    }
    __syncthreads();

    short8 ahf[4];
#pragma unroll
    for (int s = 0; s < 4; ++s)
      ahf[s] = *(const short8*)(hids + l31 * 72 + s * 16 + half * 8);

    floatx16 accl[4];
#pragma unroll
    for (int tile = 0; tile < 4; ++tile) {
#pragma unroll
      for (int i = 0; i < 16; ++i) accl[tile][i] = 0.f;
#pragma unroll
      for (int s = 0; s < 4; ++s) {
        union { short8 v; unsigned int u[4]; } wf;
#pragma unroll
        for (int jp = 0; jp < 4; ++jp) {
          int k0 = s * 16 + half * 8 + jp * 2;
          float f0 = W2[(size_t)k0 * TT + tile * 32 + l31];
          float f1 = W2[(size_t)(k0 + 1) * TT + tile * 32 + l31];
          wf.u[jp] = pkbf(f0, f1);
        }
        accl[tile] = __builtin_amdgcn_mfma_f32_32x32x16_bf16(
            ahf[s], wf.v, accl[tile], 0, 0, 0);
      }
      float bt = b2[tile * 32 + l31];
#pragma unroll
      for (int i = 0; i < 16; ++i) accl[tile][i] += bt;
    }

    float mrow[16];
#pragma unroll
    for (int r = 0; r < 16; ++r)
      mrow[r] = fmaxf(fmaxf(accl[0][r], accl[1][r]),
                      fmaxf(accl[2][r], accl[3][r]));
#pragma unroll
    for (int msk = 1; msk <= 16; msk <<= 1)
#pragma unroll
      for (int r = 0; r < 16; ++r)
        mrow[r] = fmaxf(mrow[r], __shfl_xor(mrow[r], msk, 64));
    float srow[16];
#pragma unroll
    for (int r = 0; r < 16; ++r) srow[r] = 0.f;
#pragma unroll
    for (int tile = 0; tile < 4; ++tile)
#pragma unroll
      for (int r = 0; r < 16; ++r) {
        float e = __expf(accl[tile][r] - mrow[r]);
        accl[tile][r] = e;
        srow[r] += e;
      }
#pragma unroll
    for (int msk = 1; msk <= 16; msk <<= 1)
#pragma unroll
      for (int r = 0; r < 16; ++r)
        srow[r] += __shfl_xor(srow[r], msk, 64);
#pragma unroll
    for (int r = 0; r < 16; ++r) srow[r] = 1.f / srow[r];

#pragma unroll
    for (int tile = 0; tile < 4; ++tile)
#pragma unroll
      for (int r = 0; r < 16; ++r) {
        int row = (r & 3) + 8 * (r >> 2) + 4 * half;
        attnB[(size_t)(b0 + row) * TT + tile * 32 + l31] =
            __float2half(accl[tile][r] * srow[r]);
      }

  } else if (blk < 384) {
    // ------- leaf softmax (1 tree) -> COMPACT fp16 B-frags ------------------
    float* lps = (float*)smem_raw;   // [128][12] f32 = 6144 B
    const int t0 = blk - 256;
#pragma unroll
    for (int rr = 0; rr < 2; ++rr) {
      int l = lane * 2 + rr;         // 0..127
      const float* row = lo + ((size_t)t0 * 128 + l) * CC;
      float v[CC];
      float m = -1e30f;
#pragma unroll
      for (int c = 0; c < CC; ++c) { v[c] = row[c]; m = fmaxf(m, v[c]); }
      float s = 0.f;
#pragma unroll
      for (int c = 0; c < CC; ++c) { v[c] = __expf(v[c] - m); s += v[c]; }
      float inv = 1.f / s;
      float* o = lps + l * 12;
#pragma unroll
      for (int c = 0; c < CC; ++c) o[c] = v[c] * inv;
    }
    __syncthreads();

    // layout: idx = tree*160 + s*20 + n*2 + hf  (uint4)
#pragma unroll
    for (int jj = 0; jj < 3; ++jj) {
      int idx = jj * 64 + lane;      // 0..191
      if (idx < 160) {
        int s = idx / 20, e = idx - s * 20;
        int n = e >> 1, hf = e & 1;
        unsigned int wd[4];
#pragma unroll
        for (int jp = 0; jp < 4; ++jp) {
          int l0 = s * 16 + hf * 8 + jp * 2;
          float f0 = lps[l0 * 12 + n];
          float f1 = lps[(l0 + 1) * 12 + n];
          wd[jp] = pkh(f0, f1);
        }
        ((uint4*)lpbG)[(size_t)t0 * 160 + idx] =
            make_uint4(wd[0], wd[1], wd[2], wd[3]);
      }
    }
  } else if (blk < 668) {
    // ------------- f32 -> bf16: x (256 blocks) / mask (28 blocks) -----------
    const float* src;
    unsigned short* dst;
    size_t base;
    if (blk < 640) { src = x;    dst = xbf; base = (size_t)(blk - 384) * 4096; }
    else           { src = mask; dst = mbf; base = (size_t)(blk - 640) * 4096; }
#pragma unroll
    for (int j = 0; j < 8; ++j) {
      size_t e = base + (size_t)j * 512 + (size_t)lane * 8;
      float4 a = *(const float4*)(src + e);
      float4 b = *(const float4*)(src + e + 4);
      *(short8*)(dst + e) = cvt8(a, b);
    }
  } else {
    // ------------- zero out (re-zeroed EVERY launch; atomics follow) --------
    const int base4 = (blk - 668) * 512;
#pragma unroll
    for (int j = 0; j < 8; ++j)
      ((float4*)out)[base4 + j * 64 + lane] = make_float4(0.f, 0.f, 0.f, 0.f);
  }
}

// -------- main: 2048 blocks; bg2=phys&63, tg8=phys>>6 (XCD-local slices) ----
// Per wave: 32 rows x 4 trees. Single bf[8]; launch_bounds(256,6): 85-VGPR
// cap (live ~75, no spill -- R26-verified), 24 waves/CU. LDS 8KB.
// Epilogue: atomicAdd to out; all 32 sharers of a slice are on ONE XCD.
__global__ __launch_bounds__(256, 6) void main_kernel(
    const unsigned short* __restrict__ xbf, const unsigned short* __restrict__ mbf,
    const float* __restrict__ thr, const __half* __restrict__ attnB,
    const unsigned int* __restrict__ lpbG, float* __restrict__ out) {
  __shared__ __align__(16) char smem_raw[8192];
  const int tid = threadIdx.x;
  const int wv = tid >> 6, lane = tid & 63;
  const int half = lane >> 5, l31 = lane & 31;
  const int phys = blockIdx.x;
  const int bg2 = phys & 63;                      // 0..63: rows bg2*128..+128
  const int tg8 = phys >> 6;                      // 0..31: trees tg8*4..+4
  const int bl = wv * 32 + l31;                   // own local row 0..127

  __half* zsl = (__half*)smem_raw;                // [4 tree][128 row][8]

  // early load: attn vector for own row (hides under phase 1)
  // attnB row = 128 halves = 32 uint2; group tg8 -> +tg8 (R24-verified).
  __half av[4];
  *(uint2*)av = ((const uint2*)attnB)[(size_t)(bg2 * 128 + bl) * 32 + tg8];

  // ==================== Phase 1: zs -> LDS (per-wave rows) ==================
  {
    const int m0 = tg8 * 28;
    short8 xf[8];
    const unsigned short* xr = xbf + (size_t)(bg2 * 128 + bl) * II + half * 8;
#pragma unroll
    for (int s = 0; s < 8; ++s) xf[s] = *(const short8*)(xr + s * 16);

    int mr = m0 + l31; if (mr > 895) mr = 895;   // A-pad clamp (tg8=31 only)
    const unsigned short* mrow = mbf + (size_t)mr * II + half * 8;

    floatx16 acc;
#pragma unroll
    for (int i = 0; i < 16; ++i) acc[i] = 0.f;
#pragma unroll
    for (int s = 0; s < 8; ++s) {
      short8 af = *(const short8*)(mrow + s * 16);
      acc = __builtin_amdgcn_mfma_f32_32x32x16_bf16(af, xf[s], acc, 0, 0, 0);
    }

#pragma unroll
    for (int r = 0; r < 16; ++r) {
      int row = (r & 3) + 8 * (r >> 2) + 4 * half;   // m-local 0..31
      if (row < 28) {                                // m0+row <= 895 always
        int tl = row / 7;
        int d = row - tl * 7;
        float z = acc[r] - thr[m0 + row];
        float o = 0.5f * (z / (1.f + fabsf(z)) + 1.f);
        zsl[((tl * 128) + bl) * 8 + d] = __float2half(o);
      }
    }
  }
  // NO barrier: each wave reads only the zsl rows it wrote

  // ==================== Phase 2: contraction (4 trees) ======================
  {
    const uint4* zsl4 = (const uint4*)smem_raw;
    const uint4* lpt = (const uint4*)lpbG + (size_t)tg8 * 640;

    floatx16 acc;
#pragma unroll
    for (int i = 0; i < 16; ++i) acc[i] = 0.f;

#pragma unroll
    for (int it = 0; it < 4; ++it) {
      uint4 bf[8];   // single buffer: live set fits the 85-VGPR cap
#pragma unroll
      for (int s = 0; s < 8; ++s)
        bf[s] = (l31 < CC) ? lpt[(it * 8 + s) * 20 + l31 * 2 + half]
                           : make_uint4(0u, 0u, 0u, 0u);
      uint4 sv = zsl4[it * 128 + bl];

      const __half* sh = (const __half*)&sv;
      float s0 = __half2float(sh[0]), s1 = __half2float(sh[1]);
      float s2 = __half2float(sh[2]), s3 = __half2float(sh[3]);
      float s4 = __half2float(sh[4]), s5 = __half2float(sh[5]);
      float s6 = __half2float(sh[6]);
      float A  = __half2float(av[it]);

      float s0c = 1.f - s0, s1c = 1.f - s1, s2c = 1.f - s2;
      float t0 = s0 * s1, t1 = s0c * s1, t2 = s0 * s1c, t3 = s0c * s1c;
      float pl[8];
      pl[0] = t0 * s2;  pl[1] = t1 * s2;  pl[2] = t2 * s2;  pl[3] = t3 * s2;
      pl[4] = t0 * s2c; pl[5] = t1 * s2c; pl[6] = t2 * s2c; pl[7] = t3 * s2c;
      float sel3 = half ? (1.f - s3) : s3;
      float Af = A * sel3;
      float s4c = 1.f - s4, s5c = 1.f - s5;
      float as6 = Af * s6, as6c = Af * (1.f - s6);
      float u0 = s4 * s5, u1 = s4c * s5, u2 = s4 * s5c, u3 = s4c * s5c;
      float wv8[8];
      wv8[0] = u0 * as6;  wv8[1] = u1 * as6;
      wv8[2] = u2 * as6;  wv8[3] = u3 * as6;
      wv8[4] = u0 * as6c; wv8[5] = u1 * as6c;
      wv8[6] = u2 * as6c; wv8[7] = u3 * as6c;
      __half2 pl2[4];
#pragma unroll
      for (int jp = 0; jp < 4; ++jp)
        pl2[jp] = __float22half2_rn(make_float2(pl[jp * 2], pl[jp * 2 + 1]));

#pragma unroll
      for (int s = 0; s < 8; ++s) {
        union { short8 v; __half2 h[4]; } a0;
        __half2 w2 = __half2half2(__float2half(wv8[s]));
#pragma unroll
        for (int jp = 0; jp < 4; ++jp) a0.h[jp] = __hmul2(pl2[jp], w2);
        acc = __builtin_amdgcn_mfma_f32_32x32x16_f16(
            a0.v, *(const short8*)&bf[s], acc, 0, 0, 0);
      }
    }

    // ---- epilogue: red overlays zsl -> XCD-local atomicAdd into out --------
    __syncthreads();   // every wave done reading its zsl before overlay write
    float* red = (float*)smem_raw;   // [128][10] f32 = 5120 B
    if (l31 < CC) {
#pragma unroll
      for (int r = 0; r < 16; ++r) {
        int row = (r & 3) + 8 * (r >> 2) + 4 * half;
        red[(wv * 32 + row) * 10 + l31] = acc[r];
      }
    }
    __syncthreads();
#pragma unroll
    for (int j = 0; j < 5; ++j) {
      int idx = tid + 256 * j;   // 0..1279
      atomicAdd(out + (size_t)bg2 * 1280 + idx, red[idx]);
    }
  }
}

// ---------------------------------------------------------------------------
extern "C" void kernel_launch(void* const* d_in, const int* in_sizes, int n_in,
                              void* d_out, int out_size, void* d_ws, size_t ws_size,
                              hipStream_t stream) {
  const float* x    = (const float*)d_in[0];
  const float* mask = (const float*)d_in[1];
  const float* thr  = (const float*)d_in[2];
  const float* lo   = (const float*)d_in[3];
  const float* W1   = (const float*)d_in[4];
  const float* b1   = (const float*)d_in[5];
  const float* W2   = (const float*)d_in[6];
  const float* b2   = (const float*)d_in[7];
  float* out = (float*)d_out;
  float* ws  = (float*)d_ws;

  __half*         attnB = (__half*)ws;
  unsigned int*   LPb   = (unsigned int*)(ws + OFF_LPB);
  unsigned short* xbf   = (unsigned short*)(ws + OFF_XBF);
  unsigned short* mbf   = (unsigned short*)(ws + OFF_MBF);

  prep_kernel<<<708, 64, 0, stream>>>(x, mask, lo, W1, b1, W2, b2,
                                      attnB, LPb, xbf, mbf, out);
  main_kernel<<<2048, 256, 0, stream>>>(xbf, mbf, thr, attnB, LPb, out);
}